// Round 3
// baseline (113.369 us; speedup 1.0000x reference)
//
#include <hip/hip_runtime.h>

typedef __bf16 bf16;
typedef __attribute__((ext_vector_type(4))) bf16 bf16x4;
typedef __attribute__((ext_vector_type(8))) bf16 bf16x8;
typedef __attribute__((ext_vector_type(4))) float f32x4;

namespace {

constexpr int NITERS = 50;   // R11 ERRATUM: ref's 50-iter iterate is NOT the
                             // fixed point; count must match exactly.
constexpr int KEXACT = 16;   // iterations using exact v_rcp; the remaining
                             // NITERS-KEXACT use one Newton step seeded by the
                             // previous iteration's reciprocal.

// ---- compile-time physical constants (double) ----
constexpr double csqrt(double x) {
  double s = x > 1 ? x : 1;
  for (int i = 0; i < 60; ++i) s = 0.5 * (s + x / s);
  return s;
}
constexpr double AP_D =
    ((3.667 - 1.0) / (3.667 + 0.5)) * (0.3 * (7.5 * csqrt(7.5)) / 0.0002395);
constexpr double RGAST_D = (8.3144598 / 4184.0) * 623.15;

__device__ __forceinline__ float sss_val(int i, int j) {
  // SSS[i][j] = exp(-DELTAW/(RGAS*T)); symmetric; zero outside 51x51 (pad)
  if (i > 50 || j > 50) return 0.0f;
  const float si = -0.025f + 0.001f * (float)i;
  const float sj = -0.025f + 0.001f * (float)j;
  const float acc = fmaxf(0.0f, fmaxf(si, sj) - 0.0084f);
  const float don = fminf(0.0f, fminf(si, sj) + 0.0084f);
  const float dw = (float)(AP_D * 0.5) * (si + sj) * (si + sj) + 85580.0f * acc * don;
  return expf(-dw * (float)(1.0 / RGAST_D));
}

// Row-slot -> actual sigma-row. Slots 0..47 = rows 0..47. The 3 remaining
// real rows (48,49,50) live in tile-3 class r=0 (slots 48,52,56 = g 0..2);
// ALL of classes (tp=3, r>=1) are pad.
__device__ __forceinline__ int slot2row(int slot) {
  if (slot < 48) return slot;
  if ((slot & 3) == 0 && slot < 60) return 48 + ((slot - 48) >> 2);
  return 99;   // pad -> sss_val 0 / load 0
}

__device__ __forceinline__ float fast_log(float x) {
  return __builtin_amdgcn_logf(x) * 0.69314718056f;   // ln via log2
}

// HW-verified gfx950 shape (guide §3; R4/R5/R8/R9 passed with it).
__device__ __forceinline__ f32x4 mfma(bf16x8 a, bf16x8 b, f32x4 c) {
  return __builtin_amdgcn_mfma_f32_16x16x32_bf16(a, b, c, 0, 0, 0);
}

} // namespace

// One wave = 32 solves = 2 independent CHAINS of 16 solves (8 elements x
// {pure, mix}). afr[][] (S-matrix fragments) shared by both chains.
// R3: ALL per-chain state is f32x4, register-aligned with the MFMA
// accumulators — Newton + damped update run on whole 4-vectors (v_pk_*
// pairs, zero lane-extraction moves). The 3 dead tile-3 elements ride
// along at d=1 / Gt=0 (NaN-free) to keep the loop perfectly regular.
__global__ __launch_bounds__(256, 2) void cosmo_mfma_v4(
    const float* __restrict__ my_sigma,   // [B,51]
    const float* __restrict__ v_comp,     // [B]
    const float* __restrict__ vt_sigma,   // [B,51,2]
    const float* __restrict__ v_vt,       // [B]
    float* __restrict__ out,              // [B]
    int B)
{
  const int lane = threadIdx.x & 63;
  const int wv   = threadIdx.x >> 6;
  const int s    = lane & 15;     // solve slot (C col / A-frag m pos)
  const int g    = lane >> 4;     // lane group 0..3
  const int task = s & 1;         // 0 = pure, 1 = mix
  const int ebase = blockIdx.x * 64 + wv * 16 + (s >> 1);

  int  e[2];  bool ein[2];  int ec[2];
#pragma unroll
  for (int c = 0; c < 2; ++c) {
    e[c]   = ebase + 8 * c;
    ein[c] = (e[c] < B);
    ec[c]  = ein[c] ? e[c] : 0;
  }

  // ---- per-chain prologue: rows owned by this lane (slot = 16t+4g+r) ----
  float A0[2], A1[2];
  f32x4 wh4[2][4], Gt4[2][4];     // element li=4t+r lives in [.][t][r]
#pragma unroll
  for (int c = 0; c < 2; ++c) {
    float myv[13], vtv[13];
#pragma unroll
    for (int t = 0; t < 4; ++t)
#pragma unroll
      for (int r = 0; r < 4; ++r) {
        const int li = 4 * t + r;
        if (li >= 13) continue;                  // tile3 r>=1: dead
        const int n  = slot2row(16 * t + 4 * g + r);
        const bool nv = (n < 51) && ein[c];
        const int nc = (n < 51) ? n : 50;
        myv[li] = nv ? my_sigma[(size_t)ec[c] * 51 + nc] : 0.0f;
        vtv[li] = nv ? vt_sigma[((size_t)ec[c] * 51 + nc) * 2 + 1] : 0.0f;
      }
    float pA0 = 0.f, pA1 = 0.f;
#pragma unroll
    for (int i = 0; i < 13; ++i) { pA0 += myv[i]; pA1 += vtv[i]; }
    pA0 += __shfl_xor(pA0, 16, 64); pA0 += __shfl_xor(pA0, 32, 64);
    pA1 += __shfl_xor(pA1, 16, 64); pA1 += __shfl_xor(pA1, 32, 64);
    A0[c] = pA0; A1[c] = pA1;

    const float den  = task ? (0.235f * pA0 + 0.765f * pA1) : pA0;
    const float rden = __builtin_amdgcn_rcpf(den);
    const float rdh  = 0.5f * rden;
#pragma unroll
    for (int t = 0; t < 4; ++t)
#pragma unroll
      for (int r = 0; r < 4; ++r) {
        const int li = 4 * t + r;
        if (li >= 13) { wh4[c][t][r] = 0.0f; Gt4[c][t][r] = 0.0f; continue; }
        const float num = task ? (0.235f * myv[li] + 0.765f * vtv[li]) : myv[li];
        wh4[c][t][r] = num * rdh;     // 0.5 * psigma (update coefficient)
        Gt4[c][t][r] = num * rden;    // Gt = w * G, init G = 1
      }
  }

  // ---- constant A fragments (k-permuted, row-remapped), SHARED by chains:
  //      afr[tp][kt][i] = S[row(16tp+s)][row(16*(2kt+(i>>2)) + 4g + (i&3))] ----
  bf16x8 afr[4][2];
#pragma unroll
  for (int tp = 0; tp < 4; ++tp)
#pragma unroll
    for (int kt = 0; kt < 2; ++kt) {
      bf16x8 v;
#pragma unroll
      for (int i = 0; i < 8; ++i) {
        const int kslot = 16 * (2 * kt + (i >> 2)) + 4 * g + (i & 3);
        v[i] = (bf16)sss_val(slot2row(16 * tp + s), slot2row(kslot));
      }
      afr[tp][kt] = v;
    }

  // tile-3 acc init: element 0 slot = 48+4g -> pad iff g==3 (+1 -> d=1).
  // Dead elements r=1..3 get +1 every iter -> d=1, rcp=1, Gt stays 0.
  f32x4 pad3;
  pad3[0] = (g == 3) ? 1.0f : 0.0f;
  pad3[1] = pad3[2] = pad3[3] = 1.0f;

  const bf16 bz = (bf16)0.0f;

  f32x4 rc4[2][4];               // running 1/d, register-aligned with acc
#pragma unroll
  for (int c = 0; c < 2; ++c)
#pragma unroll
    for (int t = 0; t < 4; ++t)
      rc4[c][t] = f32x4{1.0f, 1.0f, 1.0f, 1.0f};

  f32x4 acc[2][4];

  // ---- phase 1: exact reciprocal (seeds the Newton phase) ----
#pragma unroll 1
  for (int it = 0; it < KEXACT; ++it) {
#pragma unroll
    for (int c = 0; c < 2; ++c) {
      bf16x8 b0, b1;
#pragma unroll
      for (int i = 0; i < 4; ++i) {
        b0[i]     = (bf16)Gt4[c][0][i];
        b0[4 + i] = (bf16)Gt4[c][1][i];
        b1[i]     = (bf16)Gt4[c][2][i];
      }
      b1[4] = (bf16)Gt4[c][3][0]; b1[5] = bz; b1[6] = bz; b1[7] = bz;

      const f32x4 z = {};
#pragma unroll
      for (int tp = 0; tp < 3; ++tp) acc[c][tp] = mfma(afr[tp][0], b0, z);
      acc[c][3] = mfma(afr[3][0], b0, pad3);
#pragma unroll
      for (int tp = 0; tp < 4; ++tp) acc[c][tp] = mfma(afr[tp][1], b1, acc[c][tp]);
    }
#pragma unroll
    for (int c = 0; c < 2; ++c)
#pragma unroll
      for (int tp = 0; tp < 4; ++tp) {
        f32x4 rc;
#pragma unroll
        for (int r = 0; r < 4; ++r) rc[r] = __builtin_amdgcn_rcpf(acc[c][tp][r]);
        rc4[c][tp] = rc;
        Gt4[c][tp] = 0.5f * Gt4[c][tp] + wh4[c][tp] * rc;
      }
  }

  // ---- phase 2: Newton step rc <- rc*(2 - d*rc); no trans ops in loop ----
#pragma unroll 1
  for (int it = KEXACT; it < NITERS; ++it) {
#pragma unroll
    for (int c = 0; c < 2; ++c) {
      bf16x8 b0, b1;
#pragma unroll
      for (int i = 0; i < 4; ++i) {
        b0[i]     = (bf16)Gt4[c][0][i];
        b0[4 + i] = (bf16)Gt4[c][1][i];
        b1[i]     = (bf16)Gt4[c][2][i];
      }
      b1[4] = (bf16)Gt4[c][3][0]; b1[5] = bz; b1[6] = bz; b1[7] = bz;

      const f32x4 z = {};
#pragma unroll
      for (int tp = 0; tp < 3; ++tp) acc[c][tp] = mfma(afr[tp][0], b0, z);
      acc[c][3] = mfma(afr[3][0], b0, pad3);
#pragma unroll
      for (int tp = 0; tp < 4; ++tp) acc[c][tp] = mfma(afr[tp][1], b1, acc[c][tp]);
    }
#pragma unroll
    for (int c = 0; c < 2; ++c)
#pragma unroll
      for (int tp = 0; tp < 4; ++tp) {
        const f32x4 nr = 2.0f - acc[c][tp] * rc4[c][tp];   // pk_fma (neg)
        const f32x4 rc = rc4[c][tp] * nr;                  // pk_mul
        rc4[c][tp] = rc;
        Gt4[c][tp] = 0.5f * Gt4[c][tp] + wh4[c][tp] * rc;  // pk_mul + pk_fma
      }
  }

  // ---- epilogue: S_task = sum_n psigma_pure[n] * ln(G[n]), G = Gt/w ----
#pragma unroll
  for (int c = 0; c < 2; ++c) {
    const float rA0 = __builtin_amdgcn_rcpf(A0[c]);
    float Sp = 0.f;
#pragma unroll
    for (int t = 0; t < 4; ++t)
#pragma unroll
      for (int r = 0; r < 4; ++r) {
        const int li = 4 * t + r;
        if (li >= 13) continue;
        const int n = slot2row(16 * t + 4 * g + r);
        if (n < 51) {
          const float whv = wh4[c][t][r];
          const float gtv = Gt4[c][t][r];
          const float p  = (ein[c] ? my_sigma[(size_t)ec[c] * 51 + n] : 0.0f) * rA0;
          // guard w==0 (exact-0 input): p==0 there, force ln arg -> 1
          // G = Gt/w = Gt * rcp(2*wh) = Gt * 0.5 * rcp(wh)
          const float gg = (whv != 0.0f)
                             ? gtv * (0.5f * __builtin_amdgcn_rcpf(whv)) : 1.0f;
          Sp += p * __builtin_amdgcn_logf(gg);
        }
      }
    Sp += __shfl_xor(Sp, 16, 64);
    Sp += __shfl_xor(Sp, 32, 64);
    const float St = Sp * 0.69314718056f;
    const float So = __shfl_xor(St, 1, 64);   // partner task's sum

    if (task == 0 && g == 0 && ein[c]) {
      const float lng_resid = A0[c] * (1.0f / 7.5f) * (So - St);
      const float v0  = v_comp[e[c]];
      const float v1v = v_vt[e[c]];
      const float q0 = A0[c] * (1.0f / 79.53f), q1 = A1[c] * (1.0f / 79.53f);
      const float r0 = v0 * (1.0f / 66.69f), r1 = v1v * (1.0f / 66.69f);
      const float xq = 0.235f * q0 + 0.765f * q1;
      const float xr = 0.235f * r0 + 0.765f * r1;
      const float theta = 0.235f * q0 * __builtin_amdgcn_rcpf(xq);
      const float phi   = 0.235f * r0 * __builtin_amdgcn_rcpf(xr);
      const float l0 = 5.0f * (r0 - q0) - (r0 - 1.0f);
      const float l1 = 5.0f * (r1 - q1) - (r1 - 1.0f);
      const float xl = 0.235f * l0 + 0.765f * l1;
      const float lng_comb = fast_log(phi * (1.0f / 0.235f))
                           + 5.0f * q0 * fast_log(theta * __builtin_amdgcn_rcpf(phi))
                           + l0 - (phi * (1.0f / 0.235f)) * xl;
      out[e[c]] = lng_resid + lng_comb;
    }
  }
}

extern "C" void kernel_launch(void* const* d_in, const int* in_sizes, int n_in,
                              void* d_out, int out_size, void* d_ws, size_t ws_size,
                              hipStream_t stream) {
  const float* my  = (const float*)d_in[0];
  const float* vc  = (const float*)d_in[1];
  const float* vts = (const float*)d_in[2];
  const float* vvt = (const float*)d_in[3];
  float* out = (float*)d_out;
  const int B = in_sizes[1];                    // v_compound is [B]
  const int grid = (B + 63) / 64;               // 64 elements per 256-thread block
  cosmo_mfma_v4<<<grid, 256, 0, stream>>>(my, vc, vts, vvt, out, B);
}

// Round 4
// 108.226 us; speedup vs baseline: 1.0475x; 1.0475x over previous
//
#include <hip/hip_runtime.h>

typedef __bf16 bf16;
typedef __attribute__((ext_vector_type(4))) bf16 bf16x4;
typedef __attribute__((ext_vector_type(8))) bf16 bf16x8;
typedef __attribute__((ext_vector_type(4))) float f32x4;
typedef __attribute__((ext_vector_type(2))) float f32x2;

namespace {

constexpr int NITERS = 50;   // R11 ERRATUM: ref's 50-iter iterate is NOT the
                             // fixed point; count must match exactly.
constexpr int KEXACT = 16;   // updates 0..15 use exact v_rcp; 16..49 use one
                             // Newton step seeded by the previous reciprocal.

// ---- compile-time physical constants (double) ----
constexpr double csqrt(double x) {
  double s = x > 1 ? x : 1;
  for (int i = 0; i < 60; ++i) s = 0.5 * (s + x / s);
  return s;
}
constexpr double AP_D =
    ((3.667 - 1.0) / (3.667 + 0.5)) * (0.3 * (7.5 * csqrt(7.5)) / 0.0002395);
constexpr double RGAST_D = (8.3144598 / 4184.0) * 623.15;

__device__ __forceinline__ float sss_val(int i, int j) {
  // SSS[i][j] = exp(-DELTAW/(RGAS*T)); symmetric; zero outside 51x51 (pad)
  if (i > 50 || j > 50) return 0.0f;
  const float si = -0.025f + 0.001f * (float)i;
  const float sj = -0.025f + 0.001f * (float)j;
  const float acc = fmaxf(0.0f, fmaxf(si, sj) - 0.0084f);
  const float don = fminf(0.0f, fminf(si, sj) + 0.0084f);
  const float dw = (float)(AP_D * 0.5) * (si + sj) * (si + sj) + 85580.0f * acc * don;
  return expf(-dw * (float)(1.0 / RGAST_D));
}

// Row-slot -> actual sigma-row. Slots 0..47 = rows 0..47. The 3 remaining
// real rows (48,49,50) live in tile-3 class r=0 (slots 48,52,56 = g 0..2);
// ALL of classes (tp=3, r>=1) are pad.
__device__ __forceinline__ int slot2row(int slot) {
  if (slot < 48) return slot;
  if ((slot & 3) == 0 && slot < 60) return 48 + ((slot - 48) >> 2);
  return 99;   // pad -> sss_val 0 / load 0
}

__device__ __forceinline__ float fast_log(float x) {
  return __builtin_amdgcn_logf(x) * 0.69314718056f;   // ln via log2
}

// HW-verified gfx950 shape (guide §3; R4/R5/R8/R9 passed with it).
__device__ __forceinline__ f32x4 mfma(bf16x8 a, bf16x8 b, f32x4 c) {
  return __builtin_amdgcn_mfma_f32_16x16x32_bf16(a, b, c, 0, 0, 0);
}

} // namespace

// One wave = 32 solves = 2 independent CHAINS of 16 solves (8 elements x
// {pure, mix}); afr[][] (S-matrix fragments) shared by both chains.
// R4: SOFTWARE-ROTATED schedule. Per loop iteration:
//   update(c0) ; cvtb(c0) ; matvec(c0) ; update(c1) ; cvtb(c1) ; matvec(c1)
// so each chain's MFMA result is consumed only after the OTHER chain's full
// VALU update + cvt phase — MFMA latency is covered inside the iteration,
// not across the (unrotatable) loop back-edge. 50 matvecs + 50 updates per
// chain, numerics identical to R1/R2.
__global__ __launch_bounds__(256, 2) void cosmo_mfma_rot(
    const float* __restrict__ my_sigma,   // [B,51]
    const float* __restrict__ v_comp,     // [B]
    const float* __restrict__ vt_sigma,   // [B,51,2]
    const float* __restrict__ v_vt,       // [B]
    float* __restrict__ out,              // [B]
    int B)
{
  const int lane = threadIdx.x & 63;
  const int wv   = threadIdx.x >> 6;
  const int s    = lane & 15;     // solve slot (C col / A-frag m pos)
  const int g    = lane >> 4;     // lane group 0..3
  const int task = s & 1;         // 0 = pure, 1 = mix
  const int ebase = blockIdx.x * 64 + wv * 16 + (s >> 1);

  int  e[2];  bool ein[2];  int ec[2];
#pragma unroll
  for (int c = 0; c < 2; ++c) {
    e[c]   = ebase + 8 * c;
    ein[c] = (e[c] < B);
    ec[c]  = ein[c] ? e[c] : 0;
  }

  // ---- per-chain prologue: rows owned by this lane (slot = 16t+4g+r) ----
  float A0[2], A1[2];
  f32x2 wh2[2][6], Gt2[2][6];     // 12 live elements tiles 0-2 as pairs
  float wh12[2], Gt12[2];         // + 1 (tile3, r0)
#pragma unroll
  for (int c = 0; c < 2; ++c) {
    float myv[13], vtv[13];
#pragma unroll
    for (int t = 0; t < 4; ++t)
#pragma unroll
      for (int r = 0; r < 4; ++r) {
        const int li = 4 * t + r;
        if (li >= 13) continue;                  // tile3 r>=1: dead
        const int n  = slot2row(16 * t + 4 * g + r);
        const bool nv = (n < 51) && ein[c];
        const int nc = (n < 51) ? n : 50;
        myv[li] = nv ? my_sigma[(size_t)ec[c] * 51 + nc] : 0.0f;
        vtv[li] = nv ? vt_sigma[((size_t)ec[c] * 51 + nc) * 2 + 1] : 0.0f;
      }
    float pA0 = 0.f, pA1 = 0.f;
#pragma unroll
    for (int i = 0; i < 13; ++i) { pA0 += myv[i]; pA1 += vtv[i]; }
    pA0 += __shfl_xor(pA0, 16, 64); pA0 += __shfl_xor(pA0, 32, 64);
    pA1 += __shfl_xor(pA1, 16, 64); pA1 += __shfl_xor(pA1, 32, 64);
    A0[c] = pA0; A1[c] = pA1;

    const float den  = task ? (0.235f * pA0 + 0.765f * pA1) : pA0;
    const float rden = __builtin_amdgcn_rcpf(den);
    const float rdh  = 0.5f * rden;
    float w[13], wh[13];
#pragma unroll
    for (int i = 0; i < 13; ++i) {
      const float num = task ? (0.235f * myv[i] + 0.765f * vtv[i]) : myv[i];
      w[i]  = num * rden;    // psigma of this task; 0 on pads
      wh[i] = num * rdh;     // 0.5 * psigma (damped-update coefficient)
    }
#pragma unroll
    for (int p = 0; p < 6; ++p) {
      wh2[c][p][0] = wh[2 * p]; wh2[c][p][1] = wh[2 * p + 1];
      Gt2[c][p][0] = w[2 * p];  Gt2[c][p][1] = w[2 * p + 1];   // init G = 1
    }
    wh12[c] = wh[12]; Gt12[c] = w[12];
  }

  // ---- constant A fragments (k-permuted, row-remapped), SHARED by chains:
  //      afr[tp][kt][i] = S[row(16tp+s)][row(16*(2kt+(i>>2)) + 4g + (i&3))] ----
  bf16x8 afr[4][2];
#pragma unroll
  for (int tp = 0; tp < 4; ++tp)
#pragma unroll
    for (int kt = 0; kt < 2; ++kt) {
      bf16x8 v;
#pragma unroll
      for (int i = 0; i < 8; ++i) {
        const int kslot = 16 * (2 * kt + (i >> 2)) + 4 * g + (i & 3);
        v[i] = (bf16)sss_val(slot2row(16 * tp + s), slot2row(kslot));
      }
      afr[tp][kt] = v;
    }

  // tile-3 acc init: element 0 slot = 48+4g -> pad iff g==3 (+1 -> d=1).
  f32x4 pad3;
  pad3[0] = (g == 3) ? 1.0f : 0.0f;
  pad3[1] = pad3[2] = pad3[3] = 1.0f;

  const bf16 bz = (bf16)0.0f;

  f32x2 rc2[2][6];               // running 1/d per element pair, per chain
  float rc12[2] = {1.0f, 1.0f};
#pragma unroll
  for (int c = 0; c < 2; ++c)
#pragma unroll
    for (int p = 0; p < 6; ++p) { rc2[c][p][0] = 1.0f; rc2[c][p][1] = 1.0f; }

  bf16x8 b0[2], b1[2];
  f32x4  acc[2][4];

  // cvtb: Gt (f32 pairs) -> bf16 B-fragments (pairs map onto v_cvt_pk dwords)
  auto cvtb = [&](int c) {
    bf16x8 t0, t1;
#pragma unroll
    for (int p = 0; p < 4; ++p) {
      t0[2 * p]     = (bf16)Gt2[c][p][0];
      t0[2 * p + 1] = (bf16)Gt2[c][p][1];
    }
    t1[0] = (bf16)Gt2[c][4][0]; t1[1] = (bf16)Gt2[c][4][1];
    t1[2] = (bf16)Gt2[c][5][0]; t1[3] = (bf16)Gt2[c][5][1];
    t1[4] = (bf16)Gt12[c]; t1[5] = bz; t1[6] = bz; t1[7] = bz;
    b0[c] = t0; b1[c] = t1;
  };

  auto matvec = [&](int c) {
    const f32x4 z = {};
#pragma unroll
    for (int tp = 0; tp < 3; ++tp) acc[c][tp] = mfma(afr[tp][0], b0[c], z);
    acc[c][3] = mfma(afr[3][0], b0[c], pad3);
#pragma unroll
    for (int tp = 0; tp < 4; ++tp) acc[c][tp] = mfma(afr[tp][1], b1[c], acc[c][tp]);
  };

  auto upd_rcp = [&](int c) {
#pragma unroll
    for (int tp = 0; tp < 3; ++tp)
#pragma unroll
      for (int h = 0; h < 2; ++h) {
        const int p = 2 * tp + h;
        f32x2 rc;
        rc[0] = __builtin_amdgcn_rcpf(acc[c][tp][2 * h]);
        rc[1] = __builtin_amdgcn_rcpf(acc[c][tp][2 * h + 1]);
        rc2[c][p] = rc;
        Gt2[c][p] = 0.5f * Gt2[c][p] + wh2[c][p] * rc;
      }
    rc12[c] = __builtin_amdgcn_rcpf(acc[c][3][0]);
    Gt12[c] = 0.5f * Gt12[c] + wh12[c] * rc12[c];
  };

  auto upd_newton = [&](int c) {
#pragma unroll
    for (int tp = 0; tp < 3; ++tp)
#pragma unroll
      for (int h = 0; h < 2; ++h) {
        const int p = 2 * tp + h;
        f32x2 d;
        d[0] = acc[c][tp][2 * h]; d[1] = acc[c][tp][2 * h + 1];
        const f32x2 nr = 2.0f - d * rc2[c][p];
        const f32x2 rc = rc2[c][p] * nr;
        rc2[c][p] = rc;
        Gt2[c][p] = 0.5f * Gt2[c][p] + wh2[c][p] * rc;
      }
    {
      const float nr = 2.0f - acc[c][3][0] * rc12[c];
      rc12[c] = rc12[c] * nr;
      Gt12[c] = 0.5f * Gt12[c] + wh12[c] * rc12[c];
    }
  };

  // ---- rotated pipeline: d_0 in the prologue; update k consumes d_k and
  //      the following matvec computes d_{k+1} ----
  cvtb(0); matvec(0);
  cvtb(1); matvec(1);

  // phase 1: exact reciprocal updates 0..KEXACT-1 (seeds Newton)
#pragma unroll 1
  for (int it = 0; it < KEXACT; ++it) {
    upd_rcp(0); cvtb(0); matvec(0);
    upd_rcp(1); cvtb(1); matvec(1);
  }
  // phase 2: Newton updates KEXACT..NITERS-2
#pragma unroll 1
  for (int it = KEXACT; it < NITERS - 1; ++it) {
    upd_newton(0); cvtb(0); matvec(0);
    upd_newton(1); cvtb(1); matvec(1);
  }
  // final update (d_49) — no further matvec
  upd_newton(0);
  upd_newton(1);

  // ---- epilogue: S_task = sum_n psigma_pure[n] * ln(G[n]), G = Gt/w ----
#pragma unroll
  for (int c = 0; c < 2; ++c) {
    const float rA0 = __builtin_amdgcn_rcpf(A0[c]);
    float Sp = 0.f;
#pragma unroll
    for (int t = 0; t < 4; ++t)
#pragma unroll
      for (int r = 0; r < 4; ++r) {
        const int li = 4 * t + r;
        if (li >= 13) continue;
        const int n = slot2row(16 * t + 4 * g + r);
        if (n < 51) {
          const float whv = (li < 12) ? wh2[c][li >> 1][li & 1] : wh12[c];
          const float gtv = (li < 12) ? Gt2[c][li >> 1][li & 1] : Gt12[c];
          const float p  = (ein[c] ? my_sigma[(size_t)ec[c] * 51 + n] : 0.0f) * rA0;
          // guard w==0 (exact-0 input): p==0 there, force ln arg -> 1
          // G = Gt/w = Gt * rcp(2*wh) = Gt * 0.5 * rcp(wh)
          const float gg = (whv != 0.0f)
                             ? gtv * (0.5f * __builtin_amdgcn_rcpf(whv)) : 1.0f;
          Sp += p * __builtin_amdgcn_logf(gg);
        }
      }
    Sp += __shfl_xor(Sp, 16, 64);
    Sp += __shfl_xor(Sp, 32, 64);
    const float St = Sp * 0.69314718056f;
    const float So = __shfl_xor(St, 1, 64);   // partner task's sum

    if (task == 0 && g == 0 && ein[c]) {
      const float lng_resid = A0[c] * (1.0f / 7.5f) * (So - St);
      const float v0  = v_comp[e[c]];
      const float v1v = v_vt[e[c]];
      const float q0 = A0[c] * (1.0f / 79.53f), q1 = A1[c] * (1.0f / 79.53f);
      const float r0 = v0 * (1.0f / 66.69f), r1 = v1v * (1.0f / 66.69f);
      const float xq = 0.235f * q0 + 0.765f * q1;
      const float xr = 0.235f * r0 + 0.765f * r1;
      const float theta = 0.235f * q0 * __builtin_amdgcn_rcpf(xq);
      const float phi   = 0.235f * r0 * __builtin_amdgcn_rcpf(xr);
      const float l0 = 5.0f * (r0 - q0) - (r0 - 1.0f);
      const float l1 = 5.0f * (r1 - q1) - (r1 - 1.0f);
      const float xl = 0.235f * l0 + 0.765f * l1;
      const float lng_comb = fast_log(phi * (1.0f / 0.235f))
                           + 5.0f * q0 * fast_log(theta * __builtin_amdgcn_rcpf(phi))
                           + l0 - (phi * (1.0f / 0.235f)) * xl;
      out[e[c]] = lng_resid + lng_comb;
    }
  }
}

extern "C" void kernel_launch(void* const* d_in, const int* in_sizes, int n_in,
                              void* d_out, int out_size, void* d_ws, size_t ws_size,
                              hipStream_t stream) {
  const float* my  = (const float*)d_in[0];
  const float* vc  = (const float*)d_in[1];
  const float* vts = (const float*)d_in[2];
  const float* vvt = (const float*)d_in[3];
  float* out = (float*)d_out;
  const int B = in_sizes[1];                    // v_compound is [B]
  const int grid = (B + 63) / 64;               // 64 elements per 256-thread block
  cosmo_mfma_rot<<<grid, 256, 0, stream>>>(my, vc, vts, vvt, out, B);
}